// Round 18
// baseline (1073.585 us; speedup 1.0000x reference)
//
#include <hip/hip_runtime.h>

// ResidualVectorQuantizer — bit-exact vs harness np ref (VERIFIED R14, absmax 0):
//   rr/cc: pure sequential sum of rounded squares:
//     s = ((((((p0+p1)+p2)+p3)+p4)+p5)+p6)+p7,  p_i = fl(x_i*x_i)
//   dot (einsum SSE3): l_i = fl(m_i+m_{i+4}), dot = (l0+l1)+(l2+l3)
//   dist = fl(fl(rr+cc) - fl(2*dot)); argmin first-min strict <.
//   Updates: exactly-rounded f32 elementwise.
// DO NOT change any arithmetic order / introduce FMA / contraction.
//
// R18 = R15/R16/R17 resubmitted (three consecutive container infra
// failures; kernel never ran): TPT 2->1 (grid 512->1024 blocks,
// 2->4 blocks/CU, 2->4 waves/SIMD) + k-loop unroll 4. Numerics untouched.

#define TOKENS   262144      // B*T
#define D        8
#define K        1024
#define Q        8
#define LOSS_OFF 2097152
#define CODES_OFF 2097153

#define BLK      256
#define GRID     (TOKENS / BLK)           // 1024 blocks, 1 token/thread

// pure sequential sum of 8 (verified tree)
__device__ __forceinline__ float np_sum8_pureseq(const float* __restrict__ p) {
#pragma clang fp contract(off)
  float s = p[0];
  s = s + p[1]; s = s + p[2]; s = s + p[3]; s = s + p[4];
  s = s + p[5]; s = s + p[6]; s = s + p[7];
  return s;
}

// ---- prep: cc[q*K+k] = sum(c*c) pure-seq ----
__global__ __launch_bounds__(BLK) void rvq_prep(const float* __restrict__ cb,
                                                float* __restrict__ cc) {
#pragma clang fp contract(off)
  int i = blockIdx.x * BLK + threadIdx.x;   // [0, Q*K)
  const float* c = cb + i * D;
  float p[D];
#pragma unroll
  for (int d = 0; d < D; ++d) p[d] = c[d] * c[d];
  cc[i] = np_sum8_pureseq(p);
}

// ---- main: 1 token per thread ----
__global__ __launch_bounds__(BLK) void rvq_main(const float* __restrict__ x,
                                                const float* __restrict__ cb,
                                                const float* __restrict__ cct,
                                                float* __restrict__ out,
                                                double* __restrict__ partials) {
#pragma clang fp contract(off)
  __shared__ float sC[K][D];    // 32 KiB codebook (f32)
  __shared__ float sCC[K];      // 4 KiB ||c||^2
  const int tid = threadIdx.x;
  const int bt = blockIdx.x * BLK + tid;

  float rf[D];   // residual
  float qv[D];   // accumulated quantized
  {
    const float4* xp = (const float4*)(x + bt * D);
    float4 a = xp[0], b = xp[1];
    rf[0] = a.x; rf[1] = a.y; rf[2] = a.z; rf[3] = a.w;
    rf[4] = b.x; rf[5] = b.y; rf[6] = b.z; rf[7] = b.w;
#pragma unroll
    for (int d = 0; d < D; ++d) qv[d] = 0.0f;
  }
  double lossAcc = 0.0;

  for (int q = 0; q < Q; ++q) {
    __syncthreads();
    {
      const float4* src = (const float4*)(cb + q * (K * D));
      float4* dst = (float4*)sC;
      for (int i = tid; i < (K * D) / 4; i += BLK) dst[i] = src[i];
      const float* ccq = cct + q * K;
      for (int i = tid; i < K; i += BLK) sCC[i] = ccq[i];
    }
    __syncthreads();

    // rr = pure-seq sum of rounded squares (verified tree)
    float rr;
    {
      float p[D];
#pragma unroll
      for (int d = 0; d < D; ++d) p[d] = rf[d] * rf[d];
      rr = np_sum8_pureseq(p);
    }

    // argmin scan: einsum SSE3 tree (verified)
    float best = 3.402823466e+38f;
    int idx = 0;
#pragma unroll 4
    for (int k = 0; k < K; ++k) {
      const float4* row = (const float4*)sC[k];
      float4 ca = row[0], cb4 = row[1];
      float ccv = sCC[k];

      float m0 = rf[0] * ca.x, m1 = rf[1] * ca.y, m2 = rf[2] * ca.z,
            m3 = rf[3] * ca.w, m4 = rf[4] * cb4.x, m5 = rf[5] * cb4.y,
            m6 = rf[6] * cb4.z, m7 = rf[7] * cb4.w;
      float l0 = m0 + m4, l1 = m1 + m5, l2 = m2 + m6, l3 = m3 + m7;
      float dot = (l0 + l1) + (l2 + l3);
      float s = (rr + ccv) - 2.0f * dot;
      if (s < best) { best = s; idx = k; }
    }

    // f32 update chain (exactly-rounded elementwise ops)
#pragma unroll
    for (int d = 0; d < D; ++d) {
      float e = sC[idx][d];
      qv[d] = qv[d] + e;
      rf[d] = rf[d] - e;
      float f = rf[d] - e;
      lossAcc = fma((double)f, (double)f, lossAcc);
    }
    out[CODES_OFF + q * TOKENS + bt] = (float)idx;
  }

  // straight-through: out_q = f32(x + f32(q - x))
  {
    const float4* xp = (const float4*)(x + bt * D);
    float4 a = xp[0], b = xp[1];
    float xs[D];
    xs[0] = a.x; xs[1] = a.y; xs[2] = a.z; xs[3] = a.w;
    xs[4] = b.x; xs[5] = b.y; xs[6] = b.z; xs[7] = b.w;
    float o[D];
#pragma unroll
    for (int d = 0; d < D; ++d) o[d] = xs[d] + (qv[d] - xs[d]);
    float4 v;
    v.x = o[0]; v.y = o[1]; v.z = o[2]; v.w = o[3];
    ((float4*)(out + bt * D))[0] = v;
    v.x = o[4]; v.y = o[5]; v.z = o[6]; v.w = o[7];
    ((float4*)(out + bt * D))[1] = v;
  }

  // block loss reduction
  for (int off = 32; off; off >>= 1) lossAcc += __shfl_down(lossAcc, off);
  __syncthreads();
  double* red = (double*)sC;
  if ((tid & 63) == 0) red[tid >> 6] = lossAcc;
  __syncthreads();
  if (tid == 0) partials[blockIdx.x] = red[0] + red[1] + red[2] + red[3];
}

// ---- finalize loss (GRID=1024 partials) ----
__global__ __launch_bounds__(BLK) void rvq_loss(const double* __restrict__ partials,
                                                float* __restrict__ out) {
  int tid = threadIdx.x;
  double s = partials[tid] + partials[tid + BLK] +
             partials[tid + 2 * BLK] + partials[tid + 3 * BLK];
  for (int off = 32; off; off >>= 1) s += __shfl_down(s, off);
  __shared__ double red[4];
  if ((tid & 63) == 0) red[tid >> 6] = s;
  __syncthreads();
  if (tid == 0)
    out[LOSS_OFF] = (float)((red[0] + red[1] + red[2] + red[3]) *
                            (0.25 / 2097152.0));
}

extern "C" void kernel_launch(void* const* d_in, const int* in_sizes, int n_in,
                              void* d_out, int out_size, void* d_ws, size_t ws_size,
                              hipStream_t stream) {
  const float* x  = (const float*)d_in[0];
  const float* cb = (const float*)d_in[1];
  float* out = (float*)d_out;
  double* partials = (double*)d_ws;          // GRID doubles (8 KiB)
  float* cc = (float*)(partials + GRID);     // Q*K floats (32 KiB)

  rvq_prep<<<(Q * K) / BLK, BLK, 0, stream>>>(cb, cc);
  rvq_main<<<GRID, BLK, 0, stream>>>(x, cb, cc, out, partials);
  rvq_loss<<<1, BLK, 0, stream>>>(partials, out);
}

// Round 19
// 927.816 us; speedup vs baseline: 1.1571x; 1.1571x over previous
//
#include <hip/hip_runtime.h>

// ResidualVectorQuantizer — bit-exact vs harness np ref (VERIFIED R14, absmax 0):
//   rr/cc: pure sequential sum of rounded squares
//   dot (einsum SSE3): l_i = fl(m_i+m_{i+4}), dot = (l0+l1)+(l2+l3)
//   dist = fl(fl(rr+cc) - fl(2*dot)); argmin first-min strict <.
// R19 perf: lane-pair split-K (halves scan [0,512)/[512,1024), shfl combine,
// ties->lo == numpy first-min) + float2 ext-vector math (v_pk_*_f32).
// Per-token arithmetic order IDENTICAL to R14. 1024 blocks, 4 blocks/CU.

#define TOKENS   262144      // B*T
#define D        8
#define K        1024
#define Q        8
#define LOSS_OFF 2097152
#define CODES_OFF 2097153

#define BLK      256
#define GRID     (TOKENS / BLK)   // 1024 blocks; each block owns 256 tokens

typedef float v2f __attribute__((ext_vector_type(2)));

// pure sequential sum of 8 (verified tree) — scalar version for prep
__device__ __forceinline__ float np_sum8_pureseq(const float* __restrict__ p) {
#pragma clang fp contract(off)
  float s = p[0];
  s = s + p[1]; s = s + p[2]; s = s + p[3]; s = s + p[4];
  s = s + p[5]; s = s + p[6]; s = s + p[7];
  return s;
}

// ---- prep: cc[q*K+k] = sum(c*c) pure-seq ----
__global__ __launch_bounds__(BLK) void rvq_prep(const float* __restrict__ cb,
                                                float* __restrict__ cc) {
#pragma clang fp contract(off)
  int i = blockIdx.x * BLK + threadIdx.x;   // [0, Q*K)
  const float* c = cb + i * D;
  float p[D];
#pragma unroll
  for (int d = 0; d < D; ++d) p[d] = c[d] * c[d];
  cc[i] = np_sum8_pureseq(p);
}

// ---- main: lane pair (l, l+32) shares 2 tokens; halves split K ----
__global__ __launch_bounds__(BLK) void rvq_main(const float* __restrict__ x,
                                                const float* __restrict__ cb,
                                                const float* __restrict__ cct,
                                                float* __restrict__ out,
                                                double* __restrict__ partials) {
#pragma clang fp contract(off)
  __shared__ float sC[K][D];    // 32 KiB codebook
  __shared__ float sCC[K];      // 4 KiB ||c||^2
  const int tid  = threadIdx.x;
  const int wid  = tid >> 6;          // wave in block (0..3)
  const int lane = tid & 63;
  const int half = lane >> 5;         // 0: k in [0,512), 1: [512,1024)
  const int sub  = lane & 31;
  const int t0 = blockIdx.x * 256 + wid * 64 + sub;   // token A
  const int t1 = t0 + 32;                             // token B
  const int kb = half * (K / 2);

  v2f rf2[D];   // {tokenA, tokenB} residual
  v2f qv2[D];
  {
    const float4* xa = (const float4*)(x + t0 * D);
    const float4* xb = (const float4*)(x + t1 * D);
    float4 a0 = xa[0], a1 = xa[1], b0 = xb[0], b1 = xb[1];
    rf2[0] = (v2f){a0.x, b0.x}; rf2[1] = (v2f){a0.y, b0.y};
    rf2[2] = (v2f){a0.z, b0.z}; rf2[3] = (v2f){a0.w, b0.w};
    rf2[4] = (v2f){a1.x, b1.x}; rf2[5] = (v2f){a1.y, b1.y};
    rf2[6] = (v2f){a1.z, b1.z}; rf2[7] = (v2f){a1.w, b1.w};
#pragma unroll
    for (int d = 0; d < D; ++d) qv2[d] = (v2f){0.0f, 0.0f};
  }
  double lossAcc = 0.0;

  for (int q = 0; q < Q; ++q) {
    __syncthreads();
    {
      const float4* src = (const float4*)(cb + q * (K * D));
      float4* dst = (float4*)sC;
      for (int i = tid; i < (K * D) / 4; i += BLK) dst[i] = src[i];
      const float* ccq = cct + q * K;
      for (int i = tid; i < K; i += BLK) sCC[i] = ccq[i];
    }
    __syncthreads();

    // rr = pure-seq sum of rounded squares (verified tree, per component)
    v2f rr2;
    {
      v2f p[D];
#pragma unroll
      for (int d = 0; d < D; ++d) p[d] = rf2[d] * rf2[d];
      v2f s = p[0];
      s = s + p[1]; s = s + p[2]; s = s + p[3]; s = s + p[4];
      s = s + p[5]; s = s + p[6]; s = s + p[7];
      rr2 = s;
    }

    // half-scan: k in [kb, kb+512), verified einsum SSE3 tree per component
    const float* cbase = &sC[kb][0];
    const float* ccb   = &sCC[kb];
    float bestA = 3.402823466e+38f, bestB = 3.402823466e+38f;
    int ia = kb, ib = kb;
#pragma unroll 4
    for (int k = 0; k < K / 2; ++k) {
      const float4* row = (const float4*)(cbase + k * D);
      float4 ca = row[0], cb4 = row[1];
      float ccv = ccb[k];

      v2f m0 = rf2[0] * ca.x,  m1 = rf2[1] * ca.y,
          m2 = rf2[2] * ca.z,  m3 = rf2[3] * ca.w,
          m4 = rf2[4] * cb4.x, m5 = rf2[5] * cb4.y,
          m6 = rf2[6] * cb4.z, m7 = rf2[7] * cb4.w;
      v2f l0 = m0 + m4, l1 = m1 + m5, l2 = m2 + m6, l3 = m3 + m7;
      v2f dot = (l0 + l1) + (l2 + l3);
      v2f u = rr2 + ccv;          // fl(rr+cc), splat add
      v2f s = u - (dot + dot);    // dot+dot == fl(2*dot) exactly
      if (s.x < bestA) { bestA = s.x; ia = kb + k; }
      if (s.y < bestB) { bestB = s.y; ib = kb + k; }
    }

    // combine halves: lo wins ties (== numpy first-min over full K)
    float obA = __shfl_xor(bestA, 32);
    float obB = __shfl_xor(bestB, 32);
    int   oiA = __shfl_xor(ia, 32);
    int   oiB = __shfl_xor(ib, 32);
    float loA = half ? obA : bestA,  hiA = half ? bestA : obA;
    int   liA = half ? oiA : ia,     hiiA = half ? ia : oiA;
    int idxA = (loA <= hiA) ? liA : hiiA;
    float loB = half ? obB : bestB,  hiB = half ? bestB : obB;
    int   liB = half ? oiB : ib,     hiiB = half ? ib : oiB;
    int idxB = (loB <= hiB) ? liB : hiiB;

    // f32 update chain (exactly-rounded elementwise ops; both halves run
    // identically to keep rf in sync; loss counted on half 0 only)
#pragma unroll
    for (int d = 0; d < D; ++d) {
      float eA = sC[idxA][d];
      float qA = qv2[d].x + eA; qv2[d].x = qA;
      float rA = rf2[d].x - eA; rf2[d].x = rA;
      float fA = rA - eA;
      float eB = sC[idxB][d];
      float qB = qv2[d].y + eB; qv2[d].y = qB;
      float rB = rf2[d].y - eB; rf2[d].y = rB;
      float fB = rB - eB;
      if (!half) {
        lossAcc = fma((double)fA, (double)fA, lossAcc);
        lossAcc = fma((double)fB, (double)fB, lossAcc);
      }
    }
    if (!half) {
      out[CODES_OFF + q * TOKENS + t0] = (float)idxA;
      out[CODES_OFF + q * TOKENS + t1] = (float)idxB;
    }
  }

  // straight-through: out_q = f32(x + f32(q - x)) — half 0 writes
  if (!half) {
    const float4* xa = (const float4*)(x + t0 * D);
    const float4* xb = (const float4*)(x + t1 * D);
    float4 a0 = xa[0], a1 = xa[1], b0 = xb[0], b1 = xb[1];
    float xsA[D] = {a0.x, a0.y, a0.z, a0.w, a1.x, a1.y, a1.z, a1.w};
    float xsB[D] = {b0.x, b0.y, b0.z, b0.w, b1.x, b1.y, b1.z, b1.w};
    float oA[D], oB[D];
#pragma unroll
    for (int d = 0; d < D; ++d) {
      oA[d] = xsA[d] + (qv2[d].x - xsA[d]);
      oB[d] = xsB[d] + (qv2[d].y - xsB[d]);
    }
    float4 v;
    v.x = oA[0]; v.y = oA[1]; v.z = oA[2]; v.w = oA[3];
    ((float4*)(out + t0 * D))[0] = v;
    v.x = oA[4]; v.y = oA[5]; v.z = oA[6]; v.w = oA[7];
    ((float4*)(out + t0 * D))[1] = v;
    v.x = oB[0]; v.y = oB[1]; v.z = oB[2]; v.w = oB[3];
    ((float4*)(out + t1 * D))[0] = v;
    v.x = oB[4]; v.y = oB[5]; v.z = oB[6]; v.w = oB[7];
    ((float4*)(out + t1 * D))[1] = v;
  }

  // block loss reduction (half-1 lanes contribute 0)
  for (int off = 32; off; off >>= 1) lossAcc += __shfl_down(lossAcc, off);
  __syncthreads();
  double* red = (double*)sC;
  if ((tid & 63) == 0) red[tid >> 6] = lossAcc;
  __syncthreads();
  if (tid == 0) partials[blockIdx.x] = red[0] + red[1] + red[2] + red[3];
}

// ---- finalize loss (GRID=1024 partials) ----
__global__ __launch_bounds__(BLK) void rvq_loss(const double* __restrict__ partials,
                                                float* __restrict__ out) {
  int tid = threadIdx.x;
  double s = partials[tid] + partials[tid + BLK] +
             partials[tid + 2 * BLK] + partials[tid + 3 * BLK];
  for (int off = 32; off; off >>= 1) s += __shfl_down(s, off);
  __shared__ double red[4];
  if ((tid & 63) == 0) red[tid >> 6] = s;
  __syncthreads();
  if (tid == 0)
    out[LOSS_OFF] = (float)((red[0] + red[1] + red[2] + red[3]) *
                            (0.25 / 2097152.0));
}

extern "C" void kernel_launch(void* const* d_in, const int* in_sizes, int n_in,
                              void* d_out, int out_size, void* d_ws, size_t ws_size,
                              hipStream_t stream) {
  const float* x  = (const float*)d_in[0];
  const float* cb = (const float*)d_in[1];
  float* out = (float*)d_out;
  double* partials = (double*)d_ws;          // GRID doubles (8 KiB)
  float* cc = (float*)(partials + GRID);     // Q*K floats (32 KiB)

  rvq_prep<<<(Q * K) / BLK, BLK, 0, stream>>>(cb, cc);
  rvq_main<<<GRID, BLK, 0, stream>>>(x, cb, cc, out, partials);
  rvq_loss<<<1, BLK, 0, stream>>>(partials, out);
}

// Round 20
// 885.767 us; speedup vs baseline: 1.2120x; 1.0475x over previous
//
#include <hip/hip_runtime.h>

// ResidualVectorQuantizer — bit-exact vs harness np ref (VERIFIED R14, absmax 0):
//   rr/cc: pure sequential sum of rounded squares
//   dot (einsum SSE3): l_i = fl(m_i+m_{i+4}), dot = (l0+l1)+(l2+l3)
//   dist = fl(fl(rr+cc) - fl(2*dot)); argmin first-min strict <.
// R20 perf: k-PAIR packing (v2f components = adjacent k, all-vector operands
// -> v_pk_*_f32) over TRANSPOSED LDS codebook; R19 lane-half split-K kept.
// Per-k arithmetic tree IDENTICAL to verified semantics; in-pair order k,k+1
// with strict < == numpy first-min.

#define TOKENS   262144      // B*T
#define D        8
#define K        1024
#define Q        8
#define LOSS_OFF 2097152
#define CODES_OFF 2097153

#define BLK      256
#define GRID     (TOKENS / BLK)   // 1024 blocks; each block owns 256 tokens

typedef float v2f __attribute__((ext_vector_type(2)));

// pure sequential sum of 8 (verified tree)
__device__ __forceinline__ float np_sum8_pureseq(const float* __restrict__ p) {
#pragma clang fp contract(off)
  float s = p[0];
  s = s + p[1]; s = s + p[2]; s = s + p[3]; s = s + p[4];
  s = s + p[5]; s = s + p[6]; s = s + p[7];
  return s;
}

// ---- prep: cc[q*K+k] = sum(c*c) pure-seq ----
__global__ __launch_bounds__(BLK) void rvq_prep(const float* __restrict__ cb,
                                                float* __restrict__ cc) {
#pragma clang fp contract(off)
  int i = blockIdx.x * BLK + threadIdx.x;   // [0, Q*K)
  const float* c = cb + i * D;
  float p[D];
#pragma unroll
  for (int d = 0; d < D; ++d) p[d] = c[d] * c[d];
  cc[i] = np_sum8_pureseq(p);
}

// ---- main: lane pair (l, l+32) shares 2 tokens; halves split K; k-pair pk ----
__global__ __launch_bounds__(BLK) void rvq_main(const float* __restrict__ x,
                                                const float* __restrict__ cb,
                                                const float* __restrict__ cct,
                                                float* __restrict__ out,
                                                double* __restrict__ partials) {
#pragma clang fp contract(off)
  __shared__ float sCT[D][K];   // 32 KiB TRANSPOSED codebook: sCT[d][k]
  __shared__ float sCC[K];      // 4 KiB ||c||^2
  const int tid  = threadIdx.x;
  const int wid  = tid >> 6;
  const int lane = tid & 63;
  const int half = lane >> 5;         // 0: k in [0,512), 1: [512,1024)
  const int sub  = lane & 31;
  const int t0 = blockIdx.x * 256 + wid * 64 + sub;   // token A
  const int t1 = t0 + 32;                             // token B
  const int kb = half * (K / 2);

  float rfA[D], rfB[D], qvA[D], qvB[D];
  {
    const float4* xa = (const float4*)(x + t0 * D);
    const float4* xb = (const float4*)(x + t1 * D);
    float4 a0 = xa[0], a1 = xa[1], b0 = xb[0], b1 = xb[1];
    rfA[0] = a0.x; rfA[1] = a0.y; rfA[2] = a0.z; rfA[3] = a0.w;
    rfA[4] = a1.x; rfA[5] = a1.y; rfA[6] = a1.z; rfA[7] = a1.w;
    rfB[0] = b0.x; rfB[1] = b0.y; rfB[2] = b0.z; rfB[3] = b0.w;
    rfB[4] = b1.x; rfB[5] = b1.y; rfB[6] = b1.z; rfB[7] = b1.w;
#pragma unroll
    for (int d = 0; d < D; ++d) { qvA[d] = 0.0f; qvB[d] = 0.0f; }
  }
  double lossAcc = 0.0;

  for (int q = 0; q < Q; ++q) {
    __syncthreads();
    {
      const float* cbq = cb + q * (K * D);
      float* flat = (float*)sCT;
      for (int i = tid; i < K * D; i += BLK)
        flat[i] = cbq[(i & (K - 1)) * D + (i >> 10)];   // sCT[d][k] = cb[k][d]
      const float* ccq = cct + q * K;
      for (int i = tid; i < K; i += BLK) sCC[i] = ccq[i];
    }
    __syncthreads();

    // rr = pure-seq sum of rounded squares (verified tree), broadcast pairs
    float rrA, rrB;
    {
      float p[D];
#pragma unroll
      for (int d = 0; d < D; ++d) p[d] = rfA[d] * rfA[d];
      rrA = np_sum8_pureseq(p);
#pragma unroll
      for (int d = 0; d < D; ++d) p[d] = rfB[d] * rfB[d];
      rrB = np_sum8_pureseq(p);
    }
    v2f rrA2 = (v2f){rrA, rrA}, rrB2 = (v2f){rrB, rrB};
    v2f rf2A[D], rf2B[D];
#pragma unroll
    for (int d = 0; d < D; ++d) {
      rf2A[d] = (v2f){rfA[d], rfA[d]};
      rf2B[d] = (v2f){rfB[d], rfB[d]};
    }

    // half-scan in k-pairs: components = {k, k+1}, verified tree per comp
    float bestA = 3.402823466e+38f, bestB = 3.402823466e+38f;
    int ia = kb, ib = kb;
    const float* ccb = &sCC[kb];
#pragma unroll 2
    for (int kp = 0; kp < K / 4; ++kp) {   // 256 pair-iters over this half
      const int k = kb + kp * 2;
      v2f cd[D];
#pragma unroll
      for (int d = 0; d < D; ++d)
        cd[d] = *(const v2f*)&sCT[d][k];       // ds_read_b64
      v2f cc2 = *(const v2f*)&ccb[kp * 2];

      // token A
      v2f a0 = rf2A[0] * cd[0], a1 = rf2A[1] * cd[1],
          a2 = rf2A[2] * cd[2], a3 = rf2A[3] * cd[3],
          a4 = rf2A[4] * cd[4], a5 = rf2A[5] * cd[5],
          a6 = rf2A[6] * cd[6], a7 = rf2A[7] * cd[7];
      v2f La0 = a0 + a4, La1 = a1 + a5, La2 = a2 + a6, La3 = a3 + a7;
      v2f dA = (La0 + La1) + (La2 + La3);
      v2f sA = (rrA2 + cc2) - (dA + dA);
      if (sA.x < bestA) { bestA = sA.x; ia = k; }
      if (sA.y < bestA) { bestA = sA.y; ia = k + 1; }

      // token B
      v2f b0 = rf2B[0] * cd[0], b1 = rf2B[1] * cd[1],
          b2 = rf2B[2] * cd[2], b3 = rf2B[3] * cd[3],
          b4 = rf2B[4] * cd[4], b5 = rf2B[5] * cd[5],
          b6 = rf2B[6] * cd[6], b7 = rf2B[7] * cd[7];
      v2f Lb0 = b0 + b4, Lb1 = b1 + b5, Lb2 = b2 + b6, Lb3 = b3 + b7;
      v2f dB = (Lb0 + Lb1) + (Lb2 + Lb3);
      v2f sB = (rrB2 + cc2) - (dB + dB);
      if (sB.x < bestB) { bestB = sB.x; ib = k; }
      if (sB.y < bestB) { bestB = sB.y; ib = k + 1; }
    }

    // combine halves: lo wins ties (== numpy first-min over full K)
    float obA = __shfl_xor(bestA, 32);
    float obB = __shfl_xor(bestB, 32);
    int   oiA = __shfl_xor(ia, 32);
    int   oiB = __shfl_xor(ib, 32);
    float loA = half ? obA : bestA,  hiA = half ? bestA : obA;
    int   liA = half ? oiA : ia,     hiiA = half ? ia : oiA;
    int idxA = (loA <= hiA) ? liA : hiiA;
    float loB = half ? obB : bestB,  hiB = half ? bestB : obB;
    int   liB = half ? oiB : ib,     hiiB = half ? ib : oiB;
    int idxB = (loB <= hiB) ? liB : hiiB;

    // f32 update chain (gather from transposed layout; both halves in sync)
#pragma unroll
    for (int d = 0; d < D; ++d) {
      float eA = sCT[d][idxA];
      qvA[d] = qvA[d] + eA;
      rfA[d] = rfA[d] - eA;
      float fA = rfA[d] - eA;
      float eB = sCT[d][idxB];
      qvB[d] = qvB[d] + eB;
      rfB[d] = rfB[d] - eB;
      float fB = rfB[d] - eB;
      if (!half) {
        lossAcc = fma((double)fA, (double)fA, lossAcc);
        lossAcc = fma((double)fB, (double)fB, lossAcc);
      }
    }
    if (!half) {
      out[CODES_OFF + q * TOKENS + t0] = (float)idxA;
      out[CODES_OFF + q * TOKENS + t1] = (float)idxB;
    }
  }

  // straight-through: out_q = f32(x + f32(q - x)) — half 0 writes
  if (!half) {
    const float4* xa = (const float4*)(x + t0 * D);
    const float4* xb = (const float4*)(x + t1 * D);
    float4 a0 = xa[0], a1 = xa[1], b0 = xb[0], b1 = xb[1];
    float xsA[D] = {a0.x, a0.y, a0.z, a0.w, a1.x, a1.y, a1.z, a1.w};
    float xsB[D] = {b0.x, b0.y, b0.z, b0.w, b1.x, b1.y, b1.z, b1.w};
    float oA[D], oB[D];
#pragma unroll
    for (int d = 0; d < D; ++d) {
      oA[d] = xsA[d] + (qvA[d] - xsA[d]);
      oB[d] = xsB[d] + (qvB[d] - xsB[d]);
    }
    float4 v;
    v.x = oA[0]; v.y = oA[1]; v.z = oA[2]; v.w = oA[3];
    ((float4*)(out + t0 * D))[0] = v;
    v.x = oA[4]; v.y = oA[5]; v.z = oA[6]; v.w = oA[7];
    ((float4*)(out + t0 * D))[1] = v;
    v.x = oB[0]; v.y = oB[1]; v.z = oB[2]; v.w = oB[3];
    ((float4*)(out + t1 * D))[0] = v;
    v.x = oB[4]; v.y = oB[5]; v.z = oB[6]; v.w = oB[7];
    ((float4*)(out + t1 * D))[1] = v;
  }

  // block loss reduction (half-1 lanes contribute 0)
  for (int off = 32; off; off >>= 1) lossAcc += __shfl_down(lossAcc, off);
  __syncthreads();
  double* red = (double*)sCT;
  if ((tid & 63) == 0) red[tid >> 6] = lossAcc;
  __syncthreads();
  if (tid == 0) partials[blockIdx.x] = red[0] + red[1] + red[2] + red[3];
}

// ---- finalize loss (GRID=1024 partials) ----
__global__ __launch_bounds__(BLK) void rvq_loss(const double* __restrict__ partials,
                                                float* __restrict__ out) {
  int tid = threadIdx.x;
  double s = partials[tid] + partials[tid + BLK] +
             partials[tid + 2 * BLK] + partials[tid + 3 * BLK];
  for (int off = 32; off; off >>= 1) s += __shfl_down(s, off);
  __shared__ double red[4];
  if ((tid & 63) == 0) red[tid >> 6] = s;
  __syncthreads();
  if (tid == 0)
    out[LOSS_OFF] = (float)((red[0] + red[1] + red[2] + red[3]) *
                            (0.25 / 2097152.0));
}

extern "C" void kernel_launch(void* const* d_in, const int* in_sizes, int n_in,
                              void* d_out, int out_size, void* d_ws, size_t ws_size,
                              hipStream_t stream) {
  const float* x  = (const float*)d_in[0];
  const float* cb = (const float*)d_in[1];
  float* out = (float*)d_out;
  double* partials = (double*)d_ws;          // GRID doubles (8 KiB)
  float* cc = (float*)(partials + GRID);     // Q*K floats (32 KiB)

  rvq_prep<<<(Q * K) / BLK, BLK, 0, stream>>>(cb, cc);
  rvq_main<<<GRID, BLK, 0, stream>>>(x, cb, cc, out, partials);
  rvq_loss<<<1, BLK, 0, stream>>>(partials, out);
}